// Round 2
// baseline (261.751 us; speedup 1.0000x reference)
//
#include <hip/hip_runtime.h>

// Cutout: x [B,C,H,W] fp32, zero a LENGTH x LENGTH box centered at (cy[b], cx[b])
// across all channels. B=256, C=3, H=W=224, n_holes=1, LENGTH=16.
//
// Decomposition: the op is a 154 MB pure copy + zeroing 0.5% of pixels.
// 1) hipMemcpyAsync D2D for the bulk copy — AMD's tuned blit path measures
//    ~85% of peak (~6.8 TB/s) on MI355X, above what plain-HIP streaming
//    kernels achieve here (harness fills: 6.6 TB/s; our R0/R1 kernels: ~5).
//    Graph-capture-safe per harness rules (hipMemcpyAsync on the stream).
// 2) hole_zero_kernel: one 256-thread block per batch image; threads map to
//    the 16x16 hole box; each zeroes the pixel across the 3 channels.
//    Writes ~2.4 MB total (768 KB effective) — a few microseconds.
// Stream ordering serializes copy -> patch; exact-zero output (absmax 0).

#define B_ 256
#define C_ 3
#define H_ 224
#define W_ 224
#define HALF 8

__global__ __launch_bounds__(256) void hole_zero_kernel(
    const int* __restrict__ cy,
    const int* __restrict__ cx,
    float* __restrict__ out) {
    const int b = blockIdx.x;           // one block per batch image
    const int cyb = cy[b];              // wave-uniform scalar loads
    const int cxb = cx[b];
    const int ty = threadIdx.x >> 4;    // 0..15 within hole box
    const int tx = threadIdx.x & 15;
    const int y = cyb - HALF + ty;
    const int x = cxb - HALF + tx;
    // clip to image (holes can overhang the border)
    if ((unsigned)y < (unsigned)H_ && (unsigned)x < (unsigned)W_) {
#pragma unroll
        for (int c = 0; c < C_; ++c) {
            const int idx = ((b * C_ + c) * H_ + y) * W_ + x;   // < 2^26, int ok
            out[idx] = 0.0f;
        }
    }
}

extern "C" void kernel_launch(void* const* d_in, const int* in_sizes, int n_in,
                              void* d_out, int out_size, void* d_ws, size_t ws_size,
                              hipStream_t stream) {
    const void* x  = d_in[0];
    const int*  cy = (const int*)d_in[1];   // [1, B]
    const int*  cx = (const int*)d_in[2];   // [1, B]

    const size_t bytes = (size_t)B_ * C_ * H_ * W_ * sizeof(float);  // 154,140,672
    hipMemcpyAsync(d_out, x, bytes, hipMemcpyDeviceToDevice, stream);

    hole_zero_kernel<<<dim3(B_), 256, 0, stream>>>(cy, cx, (float*)d_out);
}

// Round 3
// 253.767 us; speedup vs baseline: 1.0315x; 1.0315x over previous
//
#include <hip/hip_runtime.h>

// Cutout: x [B,C,H,W] fp32, zero a LENGTH x LENGTH box centered at (cy[b], cx[b])
// across all channels. B=256, C=3, H=W=224, n_holes=1, LENGTH=16.
//
// Memory-bound streaming op. Floor: 154 MB read + 154 MB write ~= 49 us @ 6.3 TB/s
// (m13 float4-copy ceiling). R0 (nt, 1 float4/thr) = 250.9 total; R1 (nt,
// 7 float4/thr) = 252.9 -> per-thread batching irrelevant (TLP saturates).
// R2 (hipMemcpyAsync blit + patch) = 261.8 -> blit no faster, extra dispatch.
//
// This version: R0 structure, REGULAR cached loads/stores (nt flag removed).
// Theory: `nt` bypasses L2 no-allocate; for pure streaming, L2 write-allocate
// acts as a burst-staging buffer for the memory controller (harness fills with
// normal stores hit 6.65 TB/s; nt kernel estimated ~5.1 TB/s). Single-variable
// A/B on the nt hint.
//
// Layout: grid.y = plane index (b*C+c) -> b is wave-uniform (SALU div),
// grid.x * 256 + tid = float4 index within the 224x224 plane (12544 = 49*256,
// exact -> no bounds check). One per-thread magic-div (by 56).

typedef float floatx4 __attribute__((ext_vector_type(4)));

#define B_ 256
#define C_ 3
#define H_ 224
#define W_ 224
#define HALF 8
#define W4_ (W_ / 4)                 // 56
#define PLANE4 (H_ * W4_)            // 12544 float4 per plane
#define BLOCKS_X (PLANE4 / 256)      // 49, exact

__global__ __launch_bounds__(256) void cutout_kernel(
    const floatx4* __restrict__ x,
    const int* __restrict__ cy,
    const int* __restrict__ cx,
    floatx4* __restrict__ out) {
    const int plane = blockIdx.y;                       // b*C + c, uniform
    const int b = plane / C_;                           // uniform -> SALU
    const int ip = blockIdx.x * 256 + threadIdx.x;      // [0, PLANE4)

    const int y  = ip / W4_;                            // one magic-div
    const int x4 = ip - y * W4_;

    const long gidx = (long)plane * PLANE4 + ip;
    floatx4 v = x[gidx];                                // cached load

    const int cyb = cy[b];                              // uniform scalar load
    const int cxb = cx[b];

    if (y >= cyb - HALF && y < cyb + HALF) {
        const int x0 = x4 * 4;
        const int lo = cxb - HALF;
        const int hi = cxb + HALF;
        v.x = (x0     >= lo && x0     < hi) ? 0.0f : v.x;
        v.y = (x0 + 1 >= lo && x0 + 1 < hi) ? 0.0f : v.y;
        v.z = (x0 + 2 >= lo && x0 + 2 < hi) ? 0.0f : v.z;
        v.w = (x0 + 3 >= lo && x0 + 3 < hi) ? 0.0f : v.w;
    }

    out[gidx] = v;                                      // cached store
}

extern "C" void kernel_launch(void* const* d_in, const int* in_sizes, int n_in,
                              void* d_out, int out_size, void* d_ws, size_t ws_size,
                              hipStream_t stream) {
    const floatx4* x  = (const floatx4*)d_in[0];
    const int*     cy = (const int*)d_in[1];   // [1, B]
    const int*     cx = (const int*)d_in[2];   // [1, B]
    floatx4* out = (floatx4*)d_out;

    dim3 grid(BLOCKS_X, B_ * C_);              // 49 x 768 = 37632 blocks
    cutout_kernel<<<grid, 256, 0, stream>>>(x, cy, cx, out);
}